// Round 3
// baseline (162.098 us; speedup 1.0000x reference)
//
#include <hip/hip_runtime.h>
#include <math.h>

#define Bn  16
#define Hn  384
#define Wn  512
#define HWn (Hn * Wn)

typedef float f4 __attribute__((ext_vector_type(4)));

// Grid: 1536 blocks of 256 threads. Each block = 4 waves; each wave handles
// exactly one image row (64 lanes x 8 px = 512). Block index is swizzled so
// that (assuming round-robin block->XCD dispatch, n%8) each XCD owns a band
// of 48 consecutive rows per batch -> gather-row reuse stays in one L2.
__global__ __launch_bounds__(256) void ProjectionLayer_678604833211_kernel(
    const float* __restrict__ src,    // [B,H,W,3]
    const float* __restrict__ depth,  // [B,H,W]
    const float* __restrict__ pose,   // [B,6]
    const float* __restrict__ intr,   // [3,3]
    float* __restrict__ out)          // [B,H,W,3]
{
    __shared__ float S[16];

    const int n    = blockIdx.x;
    const int xcd  = n & 7;
    const int m    = n >> 3;          // [0,192)
    const int b    = m / 12;          // batch
    const int sub  = m - b * 12;
    const int rowblk = xcd * 12 + sub;  // [0,96) within batch

    if (threadIdx.x == 0) {
        const float fx = intr[0], cx = intr[2], fy = intr[4], cy = intr[5];
        const float tx = pose[b * 6 + 0] * 0.01f;
        const float ty = pose[b * 6 + 1] * 0.01f;
        const float tz = pose[b * 6 + 2] * 0.01f;
        const float rx = pose[b * 6 + 3] * 0.001f;
        const float ry = pose[b * 6 + 4] * 0.001f;
        const float rz = pose[b * 6 + 5] * 0.001f;
        const float cX = cosf(rx), sX = sinf(rx);
        const float cY = cosf(ry), sY = sinf(ry);
        const float cZ = cosf(rz), sZ = sinf(rz);
        // R = (Rz @ Ry) @ Rx   (match reference associativity)
        const float R00 = cZ * cY;
        const float R01 = -sZ * cX + cZ * sY * sX;
        const float R02 =  sZ * sX + cZ * sY * cX;
        const float R10 = sZ * cY;
        const float R11 =  cZ * cX + sZ * sY * sX;
        const float R12 = -cZ * sX + sZ * sY * cX;
        const float R20 = -sY;
        const float R21 = cY * sX;
        const float R22 = cY * cX;
        S[0]  = fx * R00 + cx * R20;
        S[1]  = fx * R01 + cx * R21;
        S[2]  = fx * R02 + cx * R22;
        S[3]  = fx * tx  + cx * tz;
        S[4]  = fy * R10 + cy * R20;
        S[5]  = fy * R11 + cy * R21;
        S[6]  = fy * R12 + cy * R22;
        S[7]  = fy * ty  + cy * tz;
        S[8]  = R20;
        S[9]  = R21;
        S[10] = R22;
        S[11] = tz;
        S[12] = 1.0f / fx;
        S[13] = -cx / fx;
        S[14] = 1.0f / fy;
        S[15] = -cy / fy;
    }
    __syncthreads();

    const int wave = threadIdx.x >> 6;
    const int lane = threadIdx.x & 63;
    const int row  = rowblk * 4 + wave;
    const int u0   = lane * 8;

    const float m0 = S[0],  m1 = S[1],  m2  = S[2],  m3  = S[3];
    const float m4 = S[4],  m5 = S[5],  m6  = S[6],  m7  = S[7];
    const float m8 = S[8],  m9 = S[9],  m10 = S[10], m11 = S[11];
    const float ifx = S[12], nfx = S[13], ify = S[14], nfy = S[15];

    const size_t px0 = (size_t)b * HWn + (size_t)row * Wn + u0;
    const f4 dA = __builtin_nontemporal_load((const f4*)(depth + px0));
    const f4 dB = __builtin_nontemporal_load((const f4*)(depth + px0 + 4));
    const float dv[8] = {dA.x, dA.y, dA.z, dA.w, dB.x, dB.y, dB.z, dB.w};

    const float camy_u = fmaf((float)row, ify, nfy);  // camy per unit depth
    const float* __restrict__ base = src + (size_t)b * HWn * 3;

    float o[24];

    #pragma unroll
    for (int j = 0; j < 8; ++j) {
        const float d = dv[j];
        const float camx = fmaf((float)(u0 + j), ifx, nfx) * d;
        const float camy = camy_u * d;

        const float p0 = fmaf(m0, camx, fmaf(m1, camy, fmaf(m2,  d, m3)));
        const float p1 = fmaf(m4, camx, fmaf(m5, camy, fmaf(m6,  d, m7)));
        const float p2 = fmaf(m8, camx, fmaf(m9, camy, fmaf(m10, d, m11)));

        const float inv = 1.0f / (p2 + 1e-10f);
        const float x = p0 * inv;
        const float y = p1 * inv;

        const float x0f = floorf(x), y0f = floorf(y);
        const float ax = x - x0f;
        const float ay = y - y0f;
        const float bx = (x0f + 1.0f) - x;   // match reference rounding
        const float by = (y0f + 1.0f) - y;

        const int x0 = (int)fminf(fmaxf(x0f,        0.0f), 511.0f);
        const int x1 = (int)fminf(fmaxf(x0f + 1.0f, 0.0f), 511.0f);
        const int p  = (int)fminf(fmaxf(x0f,        0.0f), 510.0f);
        const int y0 = (int)fminf(fmaxf(y0f,        0.0f), 383.0f);
        const int y1 = (int)fminf(fmaxf(y0f + 1.0f, 0.0f), 383.0f);

        // Fold border clamp into x-weights (branchless):
        //   interior: xl=bx, xh=ax; left-clamp: xl=bx+ax, xh=0;
        //   right-clamp: xl=0, xh=bx+ax.
        const bool loA = (x0 == p);
        const bool hiC = (x1 == p + 1);
        const float xl = (loA ? bx : 0.0f) + (hiC ? 0.0f : ax);
        const float xh = (loA ? 0.0f : bx) + (hiC ? ax : 0.0f);

        const float* r0 = base + (size_t)(y0 * Wn + p) * 3;
        const float* r1 = base + (size_t)(y1 * Wn + p) * 3;
        float t0[6], t1[6];
        __builtin_memcpy(t0, r0, 24);   // lo pixel + hi pixel, row y0
        __builtin_memcpy(t1, r1, 24);   // lo pixel + hi pixel, row y1

        o[j * 3 + 0] = fmaf(by, fmaf(xl, t0[0], xh * t0[3]),
                            ay * fmaf(xl, t1[0], xh * t1[3]));
        o[j * 3 + 1] = fmaf(by, fmaf(xl, t0[1], xh * t0[4]),
                            ay * fmaf(xl, t1[1], xh * t1[4]));
        o[j * 3 + 2] = fmaf(by, fmaf(xl, t0[2], xh * t0[5]),
                            ay * fmaf(xl, t1[2], xh * t1[5]));
    }

    // 96 contiguous bytes per lane, 16B-aligned (px0 % 8 == 0).
    f4* q = (f4*)(out + px0 * 3);
    #pragma unroll
    for (int k = 0; k < 6; ++k) {
        f4 s = {o[4 * k + 0], o[4 * k + 1], o[4 * k + 2], o[4 * k + 3]};
        __builtin_nontemporal_store(s, q + k);
    }
}

extern "C" void kernel_launch(void* const* d_in, const int* in_sizes, int n_in,
                              void* d_out, int out_size, void* d_ws, size_t ws_size,
                              hipStream_t stream) {
    const float* src   = (const float*)d_in[0];  // [16,384,512,3]
    const float* depth = (const float*)d_in[1];  // [16,384,512]
    const float* pose  = (const float*)d_in[2];  // [16,6]
    const float* intr  = (const float*)d_in[3];  // [3,3]
    float* out = (float*)d_out;

    dim3 grid(Bn * 96);   // 1536 blocks: 16 batches x 96 row-blocks (swizzled)
    dim3 block(256);
    ProjectionLayer_678604833211_kernel<<<grid, block, 0, stream>>>(
        src, depth, pose, intr, out);
}

// Round 4
// 108.274 us; speedup vs baseline: 1.4971x; 1.4971x over previous
//
#include <hip/hip_runtime.h>
#include <math.h>

#define Bn  16
#define Hn  384
#define Wn  512
#define HWn (Hn * Wn)

typedef float f4 __attribute__((ext_vector_type(4)));

// 1536 blocks x 256 threads. Block = 4 waves; wave = one image row
// (64 lanes x 8 px, pixel mapping u = j*64 + lane -> every load/store
// instruction is lane-contiguous). Block index swizzled so XCD n%8 owns a
// band of 48 consecutive rows per batch (gather-row reuse in one L2).
// Output staged through wave-private LDS -> 6 fully-covered 1KiB stores/row.
__global__ __launch_bounds__(256) void ProjectionLayer_678604833211_kernel(
    const float* __restrict__ src,    // [B,H,W,3]
    const float* __restrict__ depth,  // [B,H,W]
    const float* __restrict__ pose,   // [B,6]
    const float* __restrict__ intr,   // [3,3]
    float* __restrict__ out)          // [B,H,W,3]
{
    __shared__ float S[16];
    __shared__ float rowbuf[4][Wn * 3];   // 24 KiB, one 6144B slice per wave

    const int n    = blockIdx.x;
    const int xcd  = n & 7;
    const int m    = n >> 3;            // [0,192)
    const int b    = m / 12;            // batch
    const int sub  = m - b * 12;
    const int rowblk = xcd * 12 + sub;  // [0,96) within batch

    if (threadIdx.x == 0) {
        const float fx = intr[0], cx = intr[2], fy = intr[4], cy = intr[5];
        const float tx = pose[b * 6 + 0] * 0.01f;
        const float ty = pose[b * 6 + 1] * 0.01f;
        const float tz = pose[b * 6 + 2] * 0.01f;
        const float rx = pose[b * 6 + 3] * 0.001f;
        const float ry = pose[b * 6 + 4] * 0.001f;
        const float rz = pose[b * 6 + 5] * 0.001f;
        const float cX = cosf(rx), sX = sinf(rx);
        const float cY = cosf(ry), sY = sinf(ry);
        const float cZ = cosf(rz), sZ = sinf(rz);
        // R = (Rz @ Ry) @ Rx   (match reference associativity)
        const float R00 = cZ * cY;
        const float R01 = -sZ * cX + cZ * sY * sX;
        const float R02 =  sZ * sX + cZ * sY * cX;
        const float R10 = sZ * cY;
        const float R11 =  cZ * cX + sZ * sY * sX;
        const float R12 = -cZ * sX + sZ * sY * cX;
        const float R20 = -sY;
        const float R21 = cY * sX;
        const float R22 = cY * cX;
        S[0]  = fx * R00 + cx * R20;
        S[1]  = fx * R01 + cx * R21;
        S[2]  = fx * R02 + cx * R22;
        S[3]  = fx * tx  + cx * tz;
        S[4]  = fy * R10 + cy * R20;
        S[5]  = fy * R11 + cy * R21;
        S[6]  = fy * R12 + cy * R22;
        S[7]  = fy * ty  + cy * tz;
        S[8]  = R20;
        S[9]  = R21;
        S[10] = R22;
        S[11] = tz;
        S[12] = 1.0f / fx;
        S[13] = -cx / fx;
        S[14] = 1.0f / fy;
        S[15] = -cy / fy;
    }
    __syncthreads();

    const int wave = threadIdx.x >> 6;
    const int lane = threadIdx.x & 63;
    const int row  = rowblk * 4 + wave;

    const float m0 = S[0],  m1 = S[1],  m2  = S[2],  m3  = S[3];
    const float m4 = S[4],  m5 = S[5],  m6  = S[6],  m7  = S[7];
    const float m8 = S[8],  m9 = S[9],  m10 = S[10], m11 = S[11];
    const float ifx = S[12], nfx = S[13], ify = S[14], nfy = S[15];

    const size_t rowpx = (size_t)b * HWn + (size_t)row * Wn;
    const float* __restrict__ drow = depth + rowpx;

    // 8 coalesced depth loads (lane stride 4B, 256B per instruction)
    float dv[8];
    #pragma unroll
    for (int j = 0; j < 8; ++j)
        dv[j] = __builtin_nontemporal_load(drow + j * 64 + lane);

    const float camy_u = fmaf((float)row, ify, nfy);  // camy per unit depth
    const float* __restrict__ base = src + (size_t)b * HWn * 3;
    float* __restrict__ wbuf = &rowbuf[wave][0];

    #pragma unroll
    for (int j = 0; j < 8; ++j) {
        const int   u = j * 64 + lane;
        const float d = dv[j];
        const float camx = fmaf((float)u, ifx, nfx) * d;
        const float camy = camy_u * d;

        const float p0 = fmaf(m0, camx, fmaf(m1, camy, fmaf(m2,  d, m3)));
        const float p1 = fmaf(m4, camx, fmaf(m5, camy, fmaf(m6,  d, m7)));
        const float p2 = fmaf(m8, camx, fmaf(m9, camy, fmaf(m10, d, m11)));

        const float inv = 1.0f / (p2 + 1e-10f);
        const float x = p0 * inv;
        const float y = p1 * inv;

        const float x0f = floorf(x), y0f = floorf(y);
        const float ax = x - x0f;
        const float ay = y - y0f;
        const float bx = (x0f + 1.0f) - x;   // match reference rounding
        const float by = (y0f + 1.0f) - y;

        const int x0 = (int)fminf(fmaxf(x0f,        0.0f), 511.0f);
        const int x1 = (int)fminf(fmaxf(x0f + 1.0f, 0.0f), 511.0f);
        const int p  = (int)fminf(fmaxf(x0f,        0.0f), 510.0f);
        const int y0 = (int)fminf(fmaxf(y0f,        0.0f), 383.0f);
        const int y1 = (int)fminf(fmaxf(y0f + 1.0f, 0.0f), 383.0f);

        // Fold border clamp into x-weights (branchless).
        const bool loA = (x0 == p);
        const bool hiC = (x1 == p + 1);
        const float xl = (loA ? bx : 0.0f) + (hiC ? 0.0f : ax);
        const float xh = (loA ? 0.0f : bx) + (hiC ? ax : 0.0f);

        const float* r0 = base + (size_t)(y0 * Wn + p) * 3;
        const float* r1 = base + (size_t)(y1 * Wn + p) * 3;
        float t0[6], t1[6];
        __builtin_memcpy(t0, r0, 24);   // lo+hi pixel, row y0
        __builtin_memcpy(t1, r1, 24);   // lo+hi pixel, row y1

        const float o0 = fmaf(by, fmaf(xl, t0[0], xh * t0[3]),
                              ay * fmaf(xl, t1[0], xh * t1[3]));
        const float o1 = fmaf(by, fmaf(xl, t0[1], xh * t0[4]),
                              ay * fmaf(xl, t1[1], xh * t1[4]));
        const float o2 = fmaf(by, fmaf(xl, t0[2], xh * t0[5]),
                              ay * fmaf(xl, t1[2], xh * t1[5]));

        // LDS stage: word addr 3*(j*64+lane)+c -> bank 3*lane+c, conflict-free
        wbuf[u * 3 + 0] = o0;
        wbuf[u * 3 + 1] = o1;
        wbuf[u * 3 + 2] = o2;
    }

    // Wave-private readback (no barrier needed): 6 x 1KiB fully-covered
    // contiguous NT stores per row.
    float* __restrict__ orow = out + rowpx * 3;
    #pragma unroll
    for (int k = 0; k < 6; ++k) {
        f4 v = *(const f4*)&wbuf[k * 256 + lane * 4];
        __builtin_nontemporal_store(v, (f4*)(orow + k * 256 + lane * 4));
    }
}

extern "C" void kernel_launch(void* const* d_in, const int* in_sizes, int n_in,
                              void* d_out, int out_size, void* d_ws, size_t ws_size,
                              hipStream_t stream) {
    const float* src   = (const float*)d_in[0];  // [16,384,512,3]
    const float* depth = (const float*)d_in[1];  // [16,384,512]
    const float* pose  = (const float*)d_in[2];  // [16,6]
    const float* intr  = (const float*)d_in[3];  // [3,3]
    float* out = (float*)d_out;

    dim3 grid(Bn * 96);   // 16 batches x 96 row-blocks (XCD-swizzled)
    dim3 block(256);
    ProjectionLayer_678604833211_kernel<<<grid, block, 0, stream>>>(
        src, depth, pose, intr, out);
}